// Round 6
// baseline (163.196 us; speedup 1.0000x reference)
//
#include <hip/hip_runtime.h>

typedef __attribute__((ext_vector_type(8))) short short8;
typedef __attribute__((ext_vector_type(4))) float f32x4;

#define BB 64
#define TS 2000
#define NN (TS*160)
#define MB 128
#define TB 16            // ceil(2000/128)
#define NTH 576          // 9 waves
#define EPS_LOG 1.52587890625e-05f   // 2^-16

// ws layout: ushort (bf16) region then float region
#define W1F_U 0          // 40960 ushorts: [tap][ct10][kp16][col16][8]
#define W1T_U 40960      // 20480 ushorts: [tap][ct10][kp8][col16][8] (k>=41 zero)
#define W2_U  61440      // 51200 ushorts: [tap][ct10][kp20][col16][8]
#define B1C_F 56320      // float idx: b1f+b1t (160)
#define B2C_F 56480      // float idx: b2 (160)

// LDS geometry (ushort units)
#define RF 146           // feat/tenv rows: t = t0-17+r, r in [0,146)
#define RH 144           // hid rows: t = t0-16+h, h in [0,144)
#define TENV_OFF (RF*136)            // 19856
#define SM_USHORTS (RF*136 + RF*72)  // 30368 -> 60736 B

__device__ __forceinline__ unsigned short f2bf(float f) {
    union { float f; unsigned u; } v; v.f = f;
    unsigned r = v.u + 0x7FFF + ((v.u >> 16) & 1);   // RNE
    return (unsigned short)(r >> 16);
}

__global__ void repack(const float* __restrict__ W1f, const float* __restrict__ b1f,
                       const float* __restrict__ W1t, const float* __restrict__ b1t,
                       const float* __restrict__ W2,  const float* __restrict__ b2,
                       void* wsv) {
    unsigned short* wu = (unsigned short*)wsv;
    float* wf = (float*)wsv;
    int n = blockIdx.x * 256 + threadIdx.x;
    if (n < 40960) {                       // W1f
        int tap = n / 20480, m = n % 20480;
        int ct = m / 2048, m2 = m % 2048;
        int kp = m2 / 128, col = (m2 % 128) / 8, i = m2 % 8;
        int o = ct * 16 + col, c = kp * 8 + i;
        wu[W1F_U + n] = f2bf(W1f[(o * 128 + c) * 2 + tap]);
    } else if (n < 61440) {                // W1t (K padded to 64)
        int r = n - 40960;
        int tap = r / 10240, m = r % 10240;
        int ct = m / 1024, m2 = m % 1024;
        int kp = m2 / 128, col = (m2 % 128) / 8, i = m2 % 8;
        int o = ct * 16 + col, c = kp * 8 + i;
        wu[W1T_U + r] = (c < 41) ? f2bf(W1t[(o * 41 + c) * 2 + tap]) : (unsigned short)0;
    } else if (n < 112640) {               // W2
        int r = n - 61440;
        int tap = r / 25600, m = r % 25600;
        int ct = m / 2560, m2 = m % 2560;
        int kp = m2 / 128, col = (m2 % 128) / 8, i = m2 % 8;
        int o = ct * 16 + col, c = kp * 8 + i;
        wu[W2_U + r] = f2bf(W2[(o * 160 + c) * 2 + tap]);
    } else if (n < 112800) {               // b1 combined
        int o = n - 112640;
        wf[B1C_F + o] = b1f[o] + b1t[o];
    } else if (n < 112960) {               // b2 copy
        int o = n - 112800;
        wf[B2C_F + o] = b2[o];
    }
}

__global__ __launch_bounds__(NTH, 2) void td_main(
    const float* __restrict__ x,
    const float* __restrict__ feat,
    const unsigned short* __restrict__ wu,
    const float* __restrict__ wf,
    float* __restrict__ out)
{
    // 60736 B LDS. s_hid ALIASES s_feat/s_tenv: all A-fragments are loaded to
    // registers before the first hid write; a barrier separates the phases.
    __shared__ __align__(16) unsigned short smem[SM_USHORTS];
    unsigned short* s_feat = smem;             // [146][136], slot r <-> t=t0-17+r
    unsigned short* s_tenv = smem + TENV_OFF;  // [146][72], cols 0..40 data, 41..63 zero
    unsigned short* s_hid  = smem;             // [144][168], slot h <-> t=t0-16+h (ALIAS)

    const int tid = threadIdx.x;
    const int b   = blockIdx.y;
    const int t0  = blockIdx.x * MB;

    // ---- stage features -> bf16 LDS ----
    const float4* feat4 = (const float4*)feat;
    for (int idx = tid; idx < RF * 32; idx += NTH) {
        int r = idx >> 5, c4 = idx & 31;
        int t = t0 - 17 + r;
        float4 v = make_float4(0.f, 0.f, 0.f, 0.f);
        if (t >= 0 && t < TS) v = feat4[((size_t)b * TS + t) * 32 + c4];
        ushort4 h;
        h.x = f2bf(v.x); h.y = f2bf(v.y); h.z = f2bf(v.z); h.w = f2bf(v.w);
        *(ushort4*)&s_feat[r * 136 + c4 * 4] = h;
    }

    // ---- envelope -> tenv (half-wave per row, shuffle reduce) ----
    {
        const int hw = tid >> 5;     // 0..17
        const int hl = tid & 31;
        for (int r = hw; r < RF; r += NTH / 32) {
            int t = t0 - 17 + r;
            if (t >= 0 && t < TS) {
                const float4* xr = (const float4*)(x + (size_t)b * NN + (size_t)t * 160);
                float4 v = xr[hl];
                float e1 = __logf(0.25f * (fabsf(v.x) + fabsf(v.y) + fabsf(v.z) + fabsf(v.w)) + EPS_LOG);
                float e2 = 0.f;
                if (hl < 8) {
                    float4 u = xr[hl + 32];
                    e2 = __logf(0.25f * (fabsf(u.x) + fabsf(u.y) + fabsf(u.z) + fabsf(u.w)) + EPS_LOG);
                }
                float s = e1 + e2;
#pragma unroll
                for (int m = 16; m; m >>= 1) s += __shfl_xor(s, m, 32);
                float avg = s * 0.025f;
                s_tenv[r * 72 + hl] = f2bf(e1 - avg);
                if (hl < 8)        s_tenv[r * 72 + 32 + hl] = f2bf(e2 - avg);
                else if (hl == 8)  s_tenv[r * 72 + 40]      = f2bf(avg);
                else               s_tenv[r * 72 + 32 + hl] = 0;   // cols 41..63 zero
            } else {
                s_tenv[r * 72 + hl]      = 0;
                s_tenv[r * 72 + 32 + hl] = 0;
            }
        }
    }
    __syncthreads();

    const int wid  = tid >> 6;    // 0..8
    const int lane = tid & 63;
    const int lr   = lane & 15;   // A row within tile / D col
    const int lk   = lane >> 4;   // k-group / D row-group

    // =========== stage B: hid = leaky(conv1f + conv1t), tile rows h0=16*wid ===========
    {
        const int h0 = wid * 16;
        short8 fa0[4], fa1[4], ea0[2], ea1[2];
        const unsigned short* f0 = &s_feat[(h0 + lr) * 136 + lk * 8];
#pragma unroll
        for (int s = 0; s < 4; ++s) {
            fa0[s] = *(const short8*)(f0 + 32 * s);          // tap0: feat[t-1]
            fa1[s] = *(const short8*)(f0 + 136 + 32 * s);    // tap1: feat[t]
        }
        const unsigned short* e0 = &s_tenv[(h0 + lr) * 72 + lk * 8];
#pragma unroll
        for (int s = 0; s < 2; ++s) {
            ea0[s] = *(const short8*)(e0 + 32 * s);
            ea1[s] = *(const short8*)(e0 + 72 + 32 * s);
        }

        // all feat/tenv LDS reads complete -> hid may overwrite the alias region
        __syncthreads();

#pragma unroll 2
        for (int ct = 0; ct < 10; ++ct) {
            float bias = wf[B1C_F + ct * 16 + lr];
            f32x4 acc0 = {0.f, 0.f, 0.f, 0.f};
            f32x4 acc1 = {0.f, 0.f, 0.f, 0.f};
            const unsigned short* bf0 = wu + W1F_U + ct * 2048 + lk * 128 + lr * 8;
            const unsigned short* bt0 = wu + W1T_U + ct * 1024 + lk * 128 + lr * 8;
#pragma unroll
            for (int s = 0; s < 4; ++s) {
                short8 w0 = *(const short8*)(bf0 + s * 512);
                acc0 = __builtin_amdgcn_mfma_f32_16x16x32_bf16(fa0[s], w0, acc0, 0, 0, 0);
                short8 w1 = *(const short8*)(bf0 + 20480 + s * 512);
                acc1 = __builtin_amdgcn_mfma_f32_16x16x32_bf16(fa1[s], w1, acc1, 0, 0, 0);
            }
#pragma unroll
            for (int s = 0; s < 2; ++s) {
                short8 w0 = *(const short8*)(bt0 + s * 512);
                acc0 = __builtin_amdgcn_mfma_f32_16x16x32_bf16(ea0[s], w0, acc0, 0, 0, 0);
                short8 w1 = *(const short8*)(bt0 + 10240 + s * 512);
                acc1 = __builtin_amdgcn_mfma_f32_16x16x32_bf16(ea1[s], w1, acc1, 0, 0, 0);
            }
#pragma unroll
            for (int j = 0; j < 4; ++j) {
                float v = acc0[j] + acc1[j] + bias;
                v = v >= 0.f ? v : 0.2f * v;
                s_hid[(h0 + lk * 4 + j) * 168 + ct * 16 + lr] = f2bf(v);
            }
        }
    }
    __syncthreads();

    // =========== stage C: out = exp(conv2(hid)+b2) * x, tiles at t0+16*wid ===========
    if (wid < 8) {
        short8 ha0[5], ha1[5];
        const unsigned short* hb = &s_hid[(15 + wid * 16 + lr) * 168 + lk * 8];
#pragma unroll
        for (int s = 0; s < 5; ++s) {
            ha0[s] = *(const short8*)(hb + 32 * s);          // tap0: hid[t-1]
            ha1[s] = *(const short8*)(hb + 168 + 32 * s);    // tap1: hid[t]
        }
#pragma unroll 2
        for (int ct = 0; ct < 10; ++ct) {
            float b2v = wf[B2C_F + ct * 16 + lr];
            f32x4 acc0 = {0.f, 0.f, 0.f, 0.f};
            f32x4 acc1 = {0.f, 0.f, 0.f, 0.f};
            const unsigned short* b2p = wu + W2_U + ct * 2560 + lk * 128 + lr * 8;
#pragma unroll
            for (int s = 0; s < 5; ++s) {
                short8 w0 = *(const short8*)(b2p + s * 512);
                acc0 = __builtin_amdgcn_mfma_f32_16x16x32_bf16(ha0[s], w0, acc0, 0, 0, 0);
                short8 w1 = *(const short8*)(b2p + 25600 + s * 512);
                acc1 = __builtin_amdgcn_mfma_f32_16x16x32_bf16(ha1[s], w1, acc1, 0, 0, 0);
            }
#pragma unroll
            for (int j = 0; j < 4; ++j) {
                int t = t0 + wid * 16 + lk * 4 + j;
                if (t < TS) {
                    size_t off = (size_t)b * NN + (size_t)t * 160 + ct * 16 + lr;
                    out[off] = __expf(acc0[j] + acc1[j] + b2v) * x[off];
                }
            }
        }
    }
}

extern "C" void kernel_launch(void* const* d_in, const int* in_sizes, int n_in,
                              void* d_out, int out_size, void* d_ws, size_t ws_size,
                              hipStream_t stream) {
    const float* x    = (const float*)d_in[0];
    const float* feat = (const float*)d_in[1];
    const float* W1f  = (const float*)d_in[2];
    const float* b1f  = (const float*)d_in[3];
    const float* W1t  = (const float*)d_in[4];
    const float* b1t  = (const float*)d_in[5];
    const float* W2   = (const float*)d_in[6];
    const float* b2   = (const float*)d_in[7];
    float* out = (float*)d_out;

    repack<<<(112960 + 255) / 256, 256, 0, stream>>>(W1f, b1f, W1t, b1t, W2, b2, d_ws);
    td_main<<<dim3(TB, BB), NTH, 0, stream>>>(
        x, feat, (const unsigned short*)d_ws, (const float*)d_ws, out);
}

// Round 7
// 127.120 us; speedup vs baseline: 1.2838x; 1.2838x over previous
//
#include <hip/hip_runtime.h>

typedef __attribute__((ext_vector_type(8))) short short8;
typedef __attribute__((ext_vector_type(4))) float f32x4;

#define BB 64
#define TS 2000
#define NN (TS*160)
#define MB 48
#define TB 42            // ceil(2000/48)
#define NTH 640          // 10 waves: wave = output col-tile ct
#define EPS_LOG 1.52587890625e-05f   // 2^-16

// ws layout: ushort (bf16) region then float region
#define W1F_U 0          // 40960 ushorts: [tap][ct10][kp16][col16][8]
#define W1T_U 40960      // 20480 ushorts: [tap][ct10][kp8][col16][8] (k>=41 zero)
#define W2_U  61440      // 51200 ushorts: [tap][ct10][kp20][col16][8]
#define B1C_F 56320      // float idx: b1f+b1t (160)
#define B2C_F 56480      // float idx: b2 (160)

__device__ __forceinline__ unsigned short f2bf(float f) {
    union { float f; unsigned u; } v; v.f = f;
    unsigned r = v.u + 0x7FFF + ((v.u >> 16) & 1);   // RNE
    return (unsigned short)(r >> 16);
}

__global__ void repack(const float* __restrict__ W1f, const float* __restrict__ b1f,
                       const float* __restrict__ W1t, const float* __restrict__ b1t,
                       const float* __restrict__ W2,  const float* __restrict__ b2,
                       void* wsv) {
    unsigned short* wu = (unsigned short*)wsv;
    float* wf = (float*)wsv;
    int n = blockIdx.x * 256 + threadIdx.x;
    if (n < 40960) {                       // W1f
        int tap = n / 20480, m = n % 20480;
        int ct = m / 2048, m2 = m % 2048;
        int kp = m2 / 128, col = (m2 % 128) / 8, i = m2 % 8;
        int o = ct * 16 + col, c = kp * 8 + i;
        wu[W1F_U + n] = f2bf(W1f[(o * 128 + c) * 2 + tap]);
    } else if (n < 61440) {                // W1t (K padded to 64)
        int r = n - 40960;
        int tap = r / 10240, m = r % 10240;
        int ct = m / 1024, m2 = m % 1024;
        int kp = m2 / 128, col = (m2 % 128) / 8, i = m2 % 8;
        int o = ct * 16 + col, c = kp * 8 + i;
        wu[W1T_U + r] = (c < 41) ? f2bf(W1t[(o * 41 + c) * 2 + tap]) : (unsigned short)0;
    } else if (n < 112640) {               // W2
        int r = n - 61440;
        int tap = r / 25600, m = r % 25600;
        int ct = m / 2560, m2 = m % 2560;
        int kp = m2 / 128, col = (m2 % 128) / 8, i = m2 % 8;
        int o = ct * 16 + col, c = kp * 8 + i;
        wu[W2_U + r] = f2bf(W2[(o * 160 + c) * 2 + tap]);
    } else if (n < 112800) {               // b1 combined
        int o = n - 112640;
        wf[B1C_F + o] = b1f[o] + b1t[o];
    } else if (n < 112960) {               // b2 copy
        int o = n - 112800;
        wf[B2C_F + o] = b2[o];
    }
}

__global__ __launch_bounds__(NTH) void td_main(
    const float* __restrict__ x,
    const float* __restrict__ feat,
    const unsigned short* __restrict__ wu,
    const float* __restrict__ wf,
    float* __restrict__ out)
{
    __shared__ __align__(16) unsigned short s_feat[65 * 136]; // row r <-> t = t0-17+r
    __shared__ __align__(16) unsigned short s_tenv[65 * 72];  // cols 0..40 data, 41..63 zero
    __shared__ __align__(16) unsigned short s_hid [64 * 168]; // row h <-> t = t0-16+h

    const int tid  = threadIdx.x;
    const int b    = blockIdx.y;
    const int t0   = blockIdx.x * MB;
    const int wid  = tid >> 6;    // 0..9 = ct (wave-stationary output col-tile)
    const int lane = tid & 63;
    const int lr   = lane & 15;   // A row within tile / D col
    const int lk   = lane >> 4;   // k-group / D row-group
    const int ct   = wid;

    // ---- weight prologue: register-stationary for the whole block ----
    short8 wB0[6], wB1[6];   // stage B: s=0..3 feat-taps, s=4..5 tenv-taps
    {
        const unsigned short* bf0 = wu + W1F_U + ct * 2048 + lk * 128 + lr * 8;
        const unsigned short* bt0 = wu + W1T_U + ct * 1024 + lk * 128 + lr * 8;
#pragma unroll
        for (int s = 0; s < 4; ++s) {
            wB0[s] = *(const short8*)(bf0 + s * 512);
            wB1[s] = *(const short8*)(bf0 + 20480 + s * 512);
        }
#pragma unroll
        for (int s = 0; s < 2; ++s) {
            wB0[4 + s] = *(const short8*)(bt0 + s * 512);
            wB1[4 + s] = *(const short8*)(bt0 + 10240 + s * 512);
        }
    }
    short8 wC0[5], wC1[5];
    {
        const unsigned short* b2p = wu + W2_U + ct * 2560 + lk * 128 + lr * 8;
#pragma unroll
        for (int s = 0; s < 5; ++s) {
            wC0[s] = *(const short8*)(b2p + s * 512);
            wC1[s] = *(const short8*)(b2p + 25600 + s * 512);
        }
    }
    const float bias1 = wf[B1C_F + ct * 16 + lr];
    const float bias2 = wf[B2C_F + ct * 16 + lr];

    // ---- stage features -> bf16 LDS ----
    const float4* feat4 = (const float4*)feat;
    for (int idx = tid; idx < 65 * 32; idx += NTH) {
        int r = idx >> 5, c4 = idx & 31;
        int t = t0 - 17 + r;
        float4 v = make_float4(0.f, 0.f, 0.f, 0.f);
        if (t >= 0 && t < TS) v = feat4[((size_t)b * TS + t) * 32 + c4];
        ushort4 h;
        h.x = f2bf(v.x); h.y = f2bf(v.y); h.z = f2bf(v.z); h.w = f2bf(v.w);
        *(ushort4*)&s_feat[r * 136 + c4 * 4] = h;
    }

    // ---- envelope -> tenv (half-wave per row, shuffle reduce) ----
    {
        const int hw = tid >> 5;     // 0..19
        const int hl = tid & 31;
        for (int r = hw; r < 65; r += NTH / 32) {
            int t = t0 - 17 + r;
            if (t >= 0 && t < TS) {
                const float4* xr = (const float4*)(x + (size_t)b * NN + (size_t)t * 160);
                float4 v = xr[hl];
                float e1 = __logf(0.25f * (fabsf(v.x) + fabsf(v.y) + fabsf(v.z) + fabsf(v.w)) + EPS_LOG);
                float e2 = 0.f;
                if (hl < 8) {
                    float4 u = xr[hl + 32];
                    e2 = __logf(0.25f * (fabsf(u.x) + fabsf(u.y) + fabsf(u.z) + fabsf(u.w)) + EPS_LOG);
                }
                float s = e1 + e2;
#pragma unroll
                for (int m = 16; m; m >>= 1) s += __shfl_xor(s, m, 32);
                float avg = s * 0.025f;
                s_tenv[r * 72 + hl] = f2bf(e1 - avg);
                if (hl < 8)        s_tenv[r * 72 + 32 + hl] = f2bf(e2 - avg);
                else if (hl == 8)  s_tenv[r * 72 + 40]      = f2bf(avg);
                else               s_tenv[r * 72 + 32 + hl] = 0;   // cols 41..63 zero
            } else {
                s_tenv[r * 72 + hl]      = 0;
                s_tenv[r * 72 + 32 + hl] = 0;
            }
        }
    }
    __syncthreads();

    // =========== stage B: hid = leaky(conv1f+conv1t); wave ct, loop 4 time tiles ===========
#pragma unroll 2
    for (int tile = 0; tile < 4; ++tile) {
        const int h0 = tile * 16;
        const unsigned short* f0 = &s_feat[(h0 + lr) * 136 + lk * 8];
        const unsigned short* e0 = &s_tenv[(h0 + lr) * 72 + lk * 8];
        f32x4 acc0 = {0.f, 0.f, 0.f, 0.f};
        f32x4 acc1 = {0.f, 0.f, 0.f, 0.f};
#pragma unroll
        for (int s = 0; s < 4; ++s) {
            short8 a0 = *(const short8*)(f0 + 32 * s);          // feat[t-1]
            short8 a1 = *(const short8*)(f0 + 136 + 32 * s);    // feat[t]
            acc0 = __builtin_amdgcn_mfma_f32_16x16x32_bf16(a0, wB0[s], acc0, 0, 0, 0);
            acc1 = __builtin_amdgcn_mfma_f32_16x16x32_bf16(a1, wB1[s], acc1, 0, 0, 0);
        }
#pragma unroll
        for (int s = 0; s < 2; ++s) {
            short8 a0 = *(const short8*)(e0 + 32 * s);
            short8 a1 = *(const short8*)(e0 + 72 + 32 * s);
            acc0 = __builtin_amdgcn_mfma_f32_16x16x32_bf16(a0, wB0[4 + s], acc0, 0, 0, 0);
            acc1 = __builtin_amdgcn_mfma_f32_16x16x32_bf16(a1, wB1[4 + s], acc1, 0, 0, 0);
        }
#pragma unroll
        for (int j = 0; j < 4; ++j) {
            int h  = h0 + lk * 4 + j;
            int th = t0 - 16 + h;
            float v = acc0[j] + acc1[j] + bias1;
            v = v >= 0.f ? v : 0.2f * v;
            s_hid[h * 168 + ct * 16 + lr] = (th >= 0) ? f2bf(v) : (unsigned short)0;
        }
    }
    __syncthreads();

    // =========== stage C: out = exp(conv2(hid)+b2)*x; wave ct, loop 3 time tiles ===========
#pragma unroll
    for (int tile = 0; tile < 3; ++tile) {
        const unsigned short* hb = &s_hid[(15 + tile * 16 + lr) * 168 + lk * 8];
        f32x4 acc0 = {0.f, 0.f, 0.f, 0.f};
        f32x4 acc1 = {0.f, 0.f, 0.f, 0.f};
#pragma unroll
        for (int s = 0; s < 5; ++s) {
            short8 a0 = *(const short8*)(hb + 32 * s);          // hid[t-1]
            short8 a1 = *(const short8*)(hb + 168 + 32 * s);    // hid[t]
            acc0 = __builtin_amdgcn_mfma_f32_16x16x32_bf16(a0, wC0[s], acc0, 0, 0, 0);
            acc1 = __builtin_amdgcn_mfma_f32_16x16x32_bf16(a1, wC1[s], acc1, 0, 0, 0);
        }
#pragma unroll
        for (int j = 0; j < 4; ++j) {
            int t = t0 + tile * 16 + lk * 4 + j;
            if (t < TS) {
                size_t off = (size_t)b * NN + (size_t)t * 160 + ct * 16 + lr;
                out[off] = __expf(acc0[j] + acc1[j] + bias2) * x[off];
            }
        }
    }
}

extern "C" void kernel_launch(void* const* d_in, const int* in_sizes, int n_in,
                              void* d_out, int out_size, void* d_ws, size_t ws_size,
                              hipStream_t stream) {
    const float* x    = (const float*)d_in[0];
    const float* feat = (const float*)d_in[1];
    const float* W1f  = (const float*)d_in[2];
    const float* b1f  = (const float*)d_in[3];
    const float* W1t  = (const float*)d_in[4];
    const float* b1t  = (const float*)d_in[5];
    const float* W2   = (const float*)d_in[6];
    const float* b2   = (const float*)d_in[7];
    float* out = (float*)d_out;

    repack<<<(112960 + 255) / 256, 256, 0, stream>>>(W1f, b1f, W1t, b1t, W2, b2, d_ws);
    td_main<<<dim3(TB, BB), NTH, 0, stream>>>(
        x, feat, (const unsigned short*)d_ws, (const float*)d_ws, out);
}